// Round 2
// baseline (139.265 us; speedup 1.0000x reference)
//
#include <hip/hip_runtime.h>
#include <hip/hip_bf16.h>

#define NB 4
#define NC 48
#define H0 512
#define W0 512
#define NCH 17   // 1 intensity + 16 mueller
#define OUTC 51  // 17 * 3 levels

// ---------------------------------------------------------------------------
// 4x4 inverse via adjugate (row-major). Feeding row-major into the classic
// column-major cofactor code yields the row-major inverse (transpose cancels).
// ---------------------------------------------------------------------------
__device__ __forceinline__ void inv4x4(const float* m, float* o) {
    float inv[16];
    inv[0]  =  m[5]*m[10]*m[15] - m[5]*m[11]*m[14] - m[9]*m[6]*m[15] + m[9]*m[7]*m[14] + m[13]*m[6]*m[11] - m[13]*m[7]*m[10];
    inv[4]  = -m[4]*m[10]*m[15] + m[4]*m[11]*m[14] + m[8]*m[6]*m[15] - m[8]*m[7]*m[14] - m[12]*m[6]*m[11] + m[12]*m[7]*m[10];
    inv[8]  =  m[4]*m[9]*m[15]  - m[4]*m[11]*m[13] - m[8]*m[5]*m[15] + m[8]*m[7]*m[13] + m[12]*m[5]*m[11] - m[12]*m[7]*m[9];
    inv[12] = -m[4]*m[9]*m[14]  + m[4]*m[10]*m[13] + m[8]*m[5]*m[14] - m[8]*m[6]*m[13] - m[12]*m[5]*m[10] + m[12]*m[6]*m[9];
    inv[1]  = -m[1]*m[10]*m[15] + m[1]*m[11]*m[14] + m[9]*m[2]*m[15] - m[9]*m[3]*m[14] - m[13]*m[2]*m[11] + m[13]*m[3]*m[10];
    inv[5]  =  m[0]*m[10]*m[15] - m[0]*m[11]*m[14] - m[8]*m[2]*m[15] + m[8]*m[3]*m[14] + m[12]*m[2]*m[11] - m[12]*m[3]*m[10];
    inv[9]  = -m[0]*m[9]*m[15]  + m[0]*m[11]*m[13] + m[8]*m[1]*m[15] - m[8]*m[3]*m[13] - m[12]*m[1]*m[11] + m[12]*m[3]*m[9];
    inv[13] =  m[0]*m[9]*m[14]  - m[0]*m[10]*m[13] - m[8]*m[1]*m[14] + m[8]*m[2]*m[13] + m[12]*m[1]*m[10] - m[12]*m[2]*m[9];
    inv[2]  =  m[1]*m[6]*m[15]  - m[1]*m[7]*m[14]  - m[5]*m[2]*m[15] + m[5]*m[3]*m[14] + m[13]*m[2]*m[7]  - m[13]*m[3]*m[6];
    inv[6]  = -m[0]*m[6]*m[15]  + m[0]*m[7]*m[14]  + m[4]*m[2]*m[15] - m[4]*m[3]*m[14] - m[12]*m[2]*m[7]  + m[12]*m[3]*m[6];
    inv[10] =  m[0]*m[5]*m[15]  - m[0]*m[7]*m[13]  - m[4]*m[1]*m[15] + m[4]*m[3]*m[13] + m[12]*m[1]*m[7]  - m[12]*m[3]*m[5];
    inv[14] = -m[0]*m[5]*m[14]  + m[0]*m[6]*m[13]  + m[4]*m[1]*m[14] - m[4]*m[2]*m[13] - m[12]*m[1]*m[6]  + m[12]*m[2]*m[5];
    inv[3]  = -m[1]*m[6]*m[11]  + m[1]*m[7]*m[10]  + m[5]*m[2]*m[11] - m[5]*m[3]*m[10] - m[9]*m[2]*m[7]   + m[9]*m[3]*m[6];
    inv[7]  =  m[0]*m[6]*m[11]  - m[0]*m[7]*m[10]  - m[4]*m[2]*m[11] + m[4]*m[3]*m[10] + m[8]*m[2]*m[7]   - m[8]*m[3]*m[6];
    inv[11] = -m[0]*m[5]*m[11]  + m[0]*m[7]*m[9]   + m[4]*m[1]*m[11] - m[4]*m[3]*m[9]  - m[8]*m[1]*m[7]   + m[8]*m[3]*m[5];
    inv[15] =  m[0]*m[5]*m[10]  - m[0]*m[6]*m[9]   - m[4]*m[1]*m[10] + m[4]*m[2]*m[9]  + m[8]*m[1]*m[6]   - m[8]*m[2]*m[5];
    float det = m[0]*inv[0] + m[1]*inv[4] + m[2]*inv[8] + m[3]*inv[12];
    float rd = 1.0f / det;
    #pragma unroll
    for (int i = 0; i < 16; i++) o[i] = inv[i] * rd;
}

// ---------------------------------------------------------------------------
// 4x4 max pool, stride 4. out: (NB, NC, hin/4, win/4), linear index == out idx.
// ---------------------------------------------------------------------------
__global__ void maxpool_kernel(const float* __restrict__ in, float* __restrict__ out,
                               int hin, int win) {
    int ho = hin >> 2, wo = win >> 2;
    int total = NB * NC * ho * wo;
    int idx = blockIdx.x * blockDim.x + threadIdx.x;
    if (idx >= total) return;
    int ox = idx % wo;
    int oy = (idx / wo) % ho;
    int bc = idx / (wo * ho);
    const float* p = in + ((size_t)bc * hin + (size_t)oy * 4) * win + (size_t)ox * 4;
    float m = -INFINITY;
    #pragma unroll
    for (int dy = 0; dy < 4; dy++) {
        #pragma unroll
        for (int dx = 0; dx < 4; dx++) m = fmaxf(m, p[(size_t)dy * win + dx]);
    }
    out[idx] = m;
}

// ---------------------------------------------------------------------------
// Mueller features: per pixel read 48 channels (3x 4x4 mats), M = inv(A) I inv(W),
// normalize by M00, intensity = mean(I). Writes 17 channels (f32).
// cpb = channels-per-batch stride in `out` (51 for d_out level 0, 17 for ws).
// ---------------------------------------------------------------------------
__global__ void feat_kernel(const float* __restrict__ in, float* __restrict__ out,
                            int h, int w, int cpb, int ch_off) {
    int hw = h * w;
    int npix = NB * hw;
    int idx = blockIdx.x * blockDim.x + threadIdx.x;
    if (idx >= npix) return;
    int b = idx / hw;
    int p = idx - b * hw;
    const float* px = in + (size_t)b * NC * hw + p;

    float Iv[16], Av[16], Wv[16];
    #pragma unroll
    for (int k = 0; k < 16; k++) Iv[k] = px[(size_t)k * hw];
    #pragma unroll
    for (int k = 0; k < 16; k++) Av[k] = px[(size_t)(16 + k) * hw];
    #pragma unroll
    for (int k = 0; k < 16; k++) Wv[k] = px[(size_t)(32 + k) * hw];

    float iA[16], iW[16];
    inv4x4(Av, iA);
    inv4x4(Wv, iW);

    float T[16];
    #pragma unroll
    for (int r = 0; r < 4; r++)
        #pragma unroll
        for (int c = 0; c < 4; c++) {
            float s = 0.f;
            #pragma unroll
            for (int k = 0; k < 4; k++) s += iA[r * 4 + k] * Iv[k * 4 + c];
            T[r * 4 + c] = s;
        }
    float M[16];
    #pragma unroll
    for (int r = 0; r < 4; r++)
        #pragma unroll
        for (int c = 0; c < 4; c++) {
            float s = 0.f;
            #pragma unroll
            for (int k = 0; k < 4; k++) s += T[r * 4 + k] * iW[k * 4 + c];
            M[r * 4 + c] = s;
        }
    float m00 = M[0];

    float inten = 0.f;
    #pragma unroll
    for (int k = 0; k < 16; k++) inten += Iv[k];
    inten *= (1.0f / 16.0f);

    float* op = out + ((size_t)b * cpb + ch_off) * hw + p;
    op[0] = inten;
    float rm = 1.0f / m00;
    #pragma unroll
    for (int k = 0; k < 16; k++) op[(size_t)(k + 1) * hw] = M[k] * rm;
}

// ---------------------------------------------------------------------------
// Bilinear upsample (align_corners=True) from (NB, 17, h, w) f32 to
// (NB, 51, 512, 512) f32 at channel offset ch_off. Row-lerp then col-lerp,
// matching the reference order.
// ---------------------------------------------------------------------------
__global__ void upsample_kernel(const float* __restrict__ feat, float* __restrict__ out,
                                int h, int w, int ch_off) {
    int idx = blockIdx.x * blockDim.x + threadIdx.x;
    int total = NB * H0 * W0;
    if (idx >= total) return;
    int X = idx % W0;
    int Y = (idx / W0) % H0;
    int b = idx / (W0 * H0);

    float sy = (float)(h - 1) / (float)(H0 - 1);
    float sx = (float)(w - 1) / (float)(W0 - 1);
    float yf = (float)Y * sy;
    float xf = (float)X * sx;
    int y0 = (int)yf;           // non-negative -> trunc == floor
    int x0 = (int)xf;
    if (y0 > h - 1) y0 = h - 1;
    if (x0 > w - 1) x0 = w - 1;
    int y1 = min(y0 + 1, h - 1);
    int x1 = min(x0 + 1, w - 1);
    float fy = yf - (float)y0;
    float fx = xf - (float)x0;

    const float* fb = feat + (size_t)b * NCH * h * w;
    float* ob = out + ((size_t)b * OUTC + ch_off) * (size_t)(H0 * W0) + (size_t)Y * W0 + X;
    for (int c = 0; c < NCH; c++) {
        const float* fc = fb + (size_t)c * h * w;
        float v00 = fc[(size_t)y0 * w + x0];
        float v01 = fc[(size_t)y0 * w + x1];
        float v10 = fc[(size_t)y1 * w + x0];
        float v11 = fc[(size_t)y1 * w + x1];
        float a = v00 * (1.f - fy) + v10 * fy;   // row lerp at x0
        float bb = v01 * (1.f - fy) + v11 * fy;  // row lerp at x1
        float v = a * (1.f - fx) + bb * fx;      // col lerp
        ob[(size_t)c * (H0 * W0)] = v;
    }
}

extern "C" void kernel_launch(void* const* d_in, const int* in_sizes, int n_in,
                              void* d_out, int out_size, void* d_ws, size_t ws_size,
                              hipStream_t stream) {
    const float* x = (const float*)d_in[0];
    float* out = (float*)d_out;
    float* ws = (float*)d_ws;

    // workspace layout (floats)
    float* pool1 = ws;                                            // 4*48*128*128
    float* pool2 = pool1 + (size_t)NB * NC * 128 * 128;           // 4*48*32*32
    float* feat1 = pool2 + (size_t)NB * NC * 32 * 32;             // 4*17*128*128
    float* feat2 = feat1 + (size_t)NB * NCH * 128 * 128;          // 4*17*32*32

    const int BS = 256;
    int t;

    // pyramid downsample
    t = NB * NC * 128 * 128;
    maxpool_kernel<<<(t + BS - 1) / BS, BS, 0, stream>>>(x, pool1, 512, 512);
    t = NB * NC * 32 * 32;
    maxpool_kernel<<<(t + BS - 1) / BS, BS, 0, stream>>>(pool1, pool2, 128, 128);

    // level 0 features -> straight to output, channels 0..16
    t = NB * H0 * W0;
    feat_kernel<<<(t + BS - 1) / BS, BS, 0, stream>>>(x, out, H0, W0, OUTC, 0);

    // level 1/2 features -> f32 workspace
    t = NB * 128 * 128;
    feat_kernel<<<(t + BS - 1) / BS, BS, 0, stream>>>(pool1, feat1, 128, 128, NCH, 0);
    t = NB * 32 * 32;
    feat_kernel<<<(t + BS - 1) / BS, BS, 0, stream>>>(pool2, feat2, 32, 32, NCH, 0);

    // upsample to full res, channels 17..33 and 34..50
    t = NB * H0 * W0;
    upsample_kernel<<<(t + BS - 1) / BS, BS, 0, stream>>>(feat1, out, 128, 128, 17);
    upsample_kernel<<<(t + BS - 1) / BS, BS, 0, stream>>>(feat2, out, 32, 32, 34);
}